// Round 4
// baseline (141.384 us; speedup 1.0000x reference)
//
#include <hip/hip_runtime.h>
#include <math.h>

#define D 100
#define NEG_SLOPE 0.2f
#define CHUNK 16
#define ROWU 52          // uints per packed-f16 row, padded 50->52 for 16B align
#define NPB 2            // nodes (waves) per block

// compiler-only memory barrier (validated R17: same-wave LDS is pipe-ordered)
#define COMPILER_FENCE() asm volatile("" ::: "memory")

typedef _Float16 f16x2 __attribute__((ext_vector_type(2)));
union U32H2 { unsigned int u; f16x2 h; };

__device__ __forceinline__ unsigned int pkh2(float x, float y) {
    U32H2 c; c.h.x = (_Float16)x; c.h.y = (_Float16)y; return c.u;
}

// 2-wide f16 dot + fp32 accumulate: v_dot2_f32_f16
__device__ __forceinline__ float dot2u(unsigned int au, unsigned int xu, float acc) {
#if __has_builtin(__builtin_amdgcn_fdot2)
    U32H2 a, x; a.u = au; x.u = xu;
    return __builtin_amdgcn_fdot2(a.h, x.h, acc, false);
#else
    U32H2 a, x; a.u = au; x.u = xu;
    return acc + (float)a.h.x * (float)x.h.x + (float)a.h.y * (float)x.h.y;
#endif
}

// DPP cross-lane (VALU pipe).
template<int CTRL>
__device__ __forceinline__ float dppf(float x) {
    return __uint_as_float((unsigned)__builtin_amdgcn_update_dpp(
        0, (int)__float_as_uint(x), CTRL, 0xF, 0xF, true));
}
__device__ __forceinline__ float red16_max(float x) {
    x = fmaxf(x, dppf<0xB1>(x));    // quad_perm xor1
    x = fmaxf(x, dppf<0x4E>(x));    // quad_perm xor2
    x = fmaxf(x, dppf<0x124>(x));   // row_ror:4
    x = fmaxf(x, dppf<0x128>(x));   // row_ror:8
    return x;
}
__device__ __forceinline__ float red16_sum(float x) {
    x += dppf<0xB1>(x);
    x += dppf<0x4E>(x);
    x += dppf<0x124>(x);
    x += dppf<0x128>(x);
    return x;
}

// Fused prep: t < P: row_ptr boundary scatter; t < total25: fp32 -> f16 pack.
__global__ void prep_kernel(const int* __restrict__ seg,
                            int* __restrict__ row_ptr,
                            const float* __restrict__ hidden,
                            unsigned int* __restrict__ hb,
                            int n, int P, int total25)
{
    int t = blockIdx.x * blockDim.x + threadIdx.x;
    if (t < P) {
        int s0 = seg[t];
        if (t == 0)
            for (int v = 0; v <= s0; v++) row_ptr[v] = 0;
        int s1 = (t + 1 < P) ? seg[t + 1] : n;
        for (int v = s0 + 1; v <= s1; v++) row_ptr[v] = t + 1;
    }
    if (t < total25) {
        int node = t / 25, k = t - node * 25;   // 25 float4-groups per row
        float4 f = ((const float4*)hidden)[t];
        *(uint2*)&hb[node * ROWU + 2 * k] =
            make_uint2(pkh2(f.x, f.y), pkh2(f.z, f.w));
    }
}

// accumulate one uint4 (8 f16 dims) into accA[b..b+7] via v_fma_mix
#define ACCU4(b, X) do {                                                      \
    U32H2 t_;                                                                 \
    t_.u = (X).x; accA[(b)+0] = fmaf((float)t_.h.x, e, accA[(b)+0]);          \
                  accA[(b)+1] = fmaf((float)t_.h.y, e, accA[(b)+1]);          \
    t_.u = (X).y; accA[(b)+2] = fmaf((float)t_.h.x, e, accA[(b)+2]);          \
                  accA[(b)+3] = fmaf((float)t_.h.y, e, accA[(b)+3]);          \
    t_.u = (X).z; accA[(b)+4] = fmaf((float)t_.h.x, e, accA[(b)+4]);          \
                  accA[(b)+5] = fmaf((float)t_.h.y, e, accA[(b)+5]);          \
    t_.u = (X).w; accA[(b)+6] = fmaf((float)t_.h.x, e, accA[(b)+6]);          \
                  accA[(b)+7] = fmaf((float)t_.h.y, e, accA[(b)+7]);          \
} while (0)

// One wave per node, CHUNK=16, 4 lanes/pair. R4 restructure: the LDS
// staging round-trip (s_rows/s_e + phase-B reads ~27 LDS ops/chunk, ~200
// LDS-pipe cy/chunk on the per-CU-shared LDS pipe ~= 34us/CU) is replaced
// by REGISTER accumulators: e lives on all 4 lanes of a pair after the
// score shfl-combine, so each lane accumulates its quarter's 24(+4) dims
// in regs (v_fma_mix). Epilogue: DPP butterfly over the 16-lane group +
// lane-predicated float2 stores. Rescale skipped when the running max
// doesn't grow (wave-uniform, exact). LDS now: s_hwp + 2 shfl/chunk only.
__launch_bounds__(64 * NPB, 6)
__global__ void gat_agg_kernel(const float* __restrict__ hidden,
                               const float* __restrict__ W,
                               const int* __restrict__ nbr,
                               const int* __restrict__ row_ptr,
                               const unsigned int* __restrict__ hb,
                               float* __restrict__ out,
                               int n, int P)
{
    __shared__ __align__(16) unsigned int s_hwp[NPB][ROWU];       // 0.42 KB

    const int lane = threadIdx.x & 63;
    const int wid  = threadIdx.x >> 6;
    const int v    = blockIdx.x * NPB + wid;
    if (v >= n) return;          // wave-uniform exit; no block barriers used

    // hw[d] = hidden[v][d] * W[d] (fp32 product, f16-packed into LDS)
    if (lane < 50) {
        float2 h2 = ((const float2*)(hidden + (long)v * D))[lane];
        float2 w2 = ((const float2*)W)[lane];
        s_hwp[wid][lane] = pkh2(h2.x * w2.x, h2.y * w2.y);
    }
    COMPILER_FENCE();

    const int start = row_ptr[v];
    const int end   = row_ptr[v + 1];

    if (end <= start) {          // empty segment: zeros (matches reference)
        if (lane < D / 2)
            ((float2*)(out + (long)v * D))[lane] = make_float2(0.f, 0.f);
        return;
    }

    const int q  = lane >> 4;    // quarter 0..3: uint4s q*3..q*3+2 (+tail on q0)
    const int jl = lane & 15;    // pair slot within the 16-chunk
    const int t0 = q * 3;

    // hoist hw fragment into registers (loop-invariant; 14 regs)
    const uint4* hwq = ((const uint4*)&s_hwp[wid][0]) + t0;
    const uint4 a0 = hwq[0], a1 = hwq[1], a2 = hwq[2];
    uint2 at = make_uint2(0u, 0u);
    if (q == 0) at = *(const uint2*)&s_hwp[wid][48];

    // register accumulators: quarter dims 24q..24q+23, plus tail 96..99 on q0
    float accA[24];
    float accT[4];
    #pragma unroll
    for (int i = 0; i < 24; ++i) accA[i] = 0.f;
    #pragma unroll
    for (int i = 0; i < 4; ++i) accT[i] = 0.f;

    float m = -INFINITY, z = 0.f;

    for (int c = start; c < end; c += CHUNK) {
        const int  cnt = min(CHUNK, end - c);
        const bool pv  = jl < cnt;

        // neighbor index: coalesced masked load. invalid lanes use row 0
        // (finite, in-bounds, L1-hot); e=0 masks them later.
        const int nbv = pv ? nbr[c + jl] : 0;
        const uint4* row16 = ((const uint4*)hb) + nbv * (ROWU / 4) + t0;

        // ---- f16 quarter-row gather (3x16B + 8B tail on q0), fdot2 ----
        uint4 x0 = row16[0], x1 = row16[1], x2 = row16[2];
        uint2 xt = make_uint2(0u, 0u);
        if (q == 0) xt = *(const uint2*)&hb[nbv * ROWU + 48];   // dims 96..99

        float p0 = 0.f, p1 = 0.f, p2 = 0.f, p3 = 0.f;
        p0 = dot2u(a0.x, x0.x, p0);  p1 = dot2u(a0.y, x0.y, p1);
        p2 = dot2u(a0.z, x0.z, p2);  p3 = dot2u(a0.w, x0.w, p3);
        p0 = dot2u(a1.x, x1.x, p0);  p1 = dot2u(a1.y, x1.y, p1);
        p2 = dot2u(a1.z, x1.z, p2);  p3 = dot2u(a1.w, x1.w, p3);
        p0 = dot2u(a2.x, x2.x, p0);  p1 = dot2u(a2.y, x2.y, p1);
        p2 = dot2u(a2.z, x2.z, p2);  p3 = dot2u(a2.w, x2.w, p3);
        if (q == 0) {
            p0 = dot2u(at.x, xt.x, p0);
            p1 = dot2u(at.y, xt.y, p1);
        }

        float part = (p0 + p1) + (p2 + p3);
        part += __shfl_xor(part, 16, 64);    // combine quarters; after these
        part += __shfl_xor(part, 32, 64);    // ALL 4 lanes hold the pair score
        const float s = pv ? (part >= 0.f ? part : NEG_SLOPE * part)
                           : -INFINITY;

        // ---- online softmax over the 16 pairs (DPP trees, wave-uniform m) --
        const float m_new = fmaxf(m, red16_max(s));
        const float e     = pv ? __expf(s - m_new) : 0.f;
        const float gsum  = red16_sum(e);

        if (m_new != m) {                    // wave-uniform; scale==1 if equal
            const float scale = __expf(m - m_new);   // first chunk: 0
            z *= scale;
            #pragma unroll
            for (int i = 0; i < 24; ++i) accA[i] *= scale;
            #pragma unroll
            for (int i = 0; i < 4; ++i) accT[i] *= scale;
            m = m_new;
        }
        z += gsum;

        // ---- accumulate e * row into register accumulators (v_fma_mix) ----
        ACCU4(0,  x0);
        ACCU4(8,  x1);
        ACCU4(16, x2);
        if (q == 0) {
            U32H2 t_;
            t_.u = xt.x; accT[0] = fmaf((float)t_.h.x, e, accT[0]);
                         accT[1] = fmaf((float)t_.h.y, e, accT[1]);
            t_.u = xt.y; accT[2] = fmaf((float)t_.h.x, e, accT[2]);
                         accT[3] = fmaf((float)t_.h.y, e, accT[3]);
        }
    }

    // ---- epilogue: sum over the 16 pairs (lanes of each 16-group) ----
    #pragma unroll
    for (int i = 0; i < 24; ++i) accA[i] = red16_sum(accA[i]);
    #pragma unroll
    for (int i = 0; i < 4; ++i) accT[i] = red16_sum(accT[i]);

    const float inv = 1.f / z;               // z identical on all lanes
    float2* orow = (float2*)(out + (long)v * D);
    #pragma unroll
    for (int j = 0; j < 12; ++j) {           // static idx; lane-predicated
        if (jl == j)
            orow[q * 12 + j] = make_float2(accA[2 * j] * inv,
                                           accA[2 * j + 1] * inv);
    }
    if (lane == 12) orow[48] = make_float2(accT[0] * inv, accT[1] * inv);
    if (lane == 13) orow[49] = make_float2(accT[2] * inv, accT[3] * inv);
}

extern "C" void kernel_launch(void* const* d_in, const int* in_sizes, int n_in,
                              void* d_out, int out_size, void* d_ws, size_t ws_size,
                              hipStream_t stream) {
    const float* hidden = (const float*)d_in[0];
    const float* W      = (const float*)d_in[1];
    const int*   seg    = (const int*)d_in[2];
    const int*   nbr    = (const int*)d_in[3];
    float*       out    = (float*)d_out;

    const int Ddim = in_sizes[1];           // 100
    const int n    = in_sizes[0] / Ddim;    // 50000
    const int P    = in_sizes[2];           // ~1.3M pairs

    // ws layout: row_ptr (n+1 ints) | hb (n*ROWU uints, 256B-aligned)
    int* row_ptr = (int*)d_ws;
    size_t hb_off = (((size_t)(n + 1) * 4) + 255) & ~(size_t)255;
    unsigned int* hb = (unsigned int*)((char*)d_ws + hb_off);

    const int total25 = n * 25;             // float4-groups in hidden
    const int tmax    = (P > total25) ? P : total25;
    hipLaunchKernelGGL(prep_kernel, dim3((tmax + 255) / 256), dim3(256), 0, stream,
                       seg, row_ptr, hidden, hb, n, P, total25);
    hipLaunchKernelGGL(gat_agg_kernel, dim3((n + NPB - 1) / NPB), dim3(64 * NPB),
                       0, stream, hidden, W, nbr, row_ptr, hb, out, n, P);
}

// Round 5
// 134.848 us; speedup vs baseline: 1.0485x; 1.0485x over previous
//
#include <hip/hip_runtime.h>
#include <math.h>

#define D 100
#define NEG_SLOPE 0.2f
#define CHUNK 16
#define ROWU 52          // uints per packed-f16 row, padded 50->52 for 16B align
#define NPB 2            // nodes (waves) per block
#define TRW 108          // transpose-buffer row width in floats (104 + pad);
                         // stride 108 -> b128 write start-banks hit 8 distinct
                         // 4-bank slots covering all 32 banks 2-way (free, m136)

// compiler-only memory barrier (validated R17: same-wave LDS is pipe-ordered)
#define COMPILER_FENCE() asm volatile("" ::: "memory")

typedef _Float16 f16x2 __attribute__((ext_vector_type(2)));
union U32H2 { unsigned int u; f16x2 h; };

__device__ __forceinline__ unsigned int pkh2(float x, float y) {
    U32H2 c; c.h.x = (_Float16)x; c.h.y = (_Float16)y; return c.u;
}

// 2-wide f16 dot + fp32 accumulate: v_dot2_f32_f16
__device__ __forceinline__ float dot2u(unsigned int au, unsigned int xu, float acc) {
#if __has_builtin(__builtin_amdgcn_fdot2)
    U32H2 a, x; a.u = au; x.u = xu;
    return __builtin_amdgcn_fdot2(a.h, x.h, acc, false);
#else
    U32H2 a, x; a.u = au; x.u = xu;
    return acc + (float)a.h.x * (float)x.h.x + (float)a.h.y * (float)x.h.y;
#endif
}

// DPP cross-lane (VALU pipe).
template<int CTRL>
__device__ __forceinline__ float dppf(float x) {
    return __uint_as_float((unsigned)__builtin_amdgcn_update_dpp(
        0, (int)__float_as_uint(x), CTRL, 0xF, 0xF, true));
}
__device__ __forceinline__ float red16_max(float x) {
    x = fmaxf(x, dppf<0xB1>(x));    // quad_perm xor1
    x = fmaxf(x, dppf<0x4E>(x));    // quad_perm xor2
    x = fmaxf(x, dppf<0x124>(x));   // row_ror:4
    x = fmaxf(x, dppf<0x128>(x));   // row_ror:8
    return x;
}
__device__ __forceinline__ float red16_sum(float x) {
    x += dppf<0xB1>(x);
    x += dppf<0x4E>(x);
    x += dppf<0x124>(x);
    x += dppf<0x128>(x);
    return x;
}

// Fused prep: t < P: row_ptr boundary scatter; t < total25: fp32 -> f16 pack.
__global__ void prep_kernel(const int* __restrict__ seg,
                            int* __restrict__ row_ptr,
                            const float* __restrict__ hidden,
                            unsigned int* __restrict__ hb,
                            int n, int P, int total25)
{
    int t = blockIdx.x * blockDim.x + threadIdx.x;
    if (t < P) {
        int s0 = seg[t];
        if (t == 0)
            for (int v = 0; v <= s0; v++) row_ptr[v] = 0;
        int s1 = (t + 1 < P) ? seg[t + 1] : n;
        for (int v = s0 + 1; v <= s1; v++) row_ptr[v] = t + 1;
    }
    if (t < total25) {
        int node = t / 25, k = t - node * 25;   // 25 float4-groups per row
        float4 f = ((const float4*)hidden)[t];
        *(uint2*)&hb[node * ROWU + 2 * k] =
            make_uint2(pkh2(f.x, f.y), pkh2(f.z, f.w));
    }
}

// accumulate one uint4 (8 f16 dims) into accA[b..b+7] via v_fma_mix
#define ACCU4(b, X) do {                                                      \
    U32H2 t_;                                                                 \
    t_.u = (X).x; accA[(b)+0] = fmaf((float)t_.h.x, e, accA[(b)+0]);          \
                  accA[(b)+1] = fmaf((float)t_.h.y, e, accA[(b)+1]);          \
    t_.u = (X).y; accA[(b)+2] = fmaf((float)t_.h.x, e, accA[(b)+2]);          \
                  accA[(b)+3] = fmaf((float)t_.h.y, e, accA[(b)+3]);          \
    t_.u = (X).z; accA[(b)+4] = fmaf((float)t_.h.x, e, accA[(b)+4]);          \
                  accA[(b)+5] = fmaf((float)t_.h.y, e, accA[(b)+5]);          \
    t_.u = (X).w; accA[(b)+6] = fmaf((float)t_.h.x, e, accA[(b)+6]);          \
                  accA[(b)+7] = fmaf((float)t_.h.y, e, accA[(b)+7]);          \
} while (0)

// One wave per node, CHUNK=16, 4 lanes/pair. R5 = "R4 done right": register
// accumulators in the main loop (28 wave-fma, all 64 lanes useful; no s_rows
// staging, no s_e, no phase-B LDS reads -> per-chunk LDS drops 208->12 cy),
// but the cross-pair reduction is ONE LDS transpose per NODE (7 b128 writes
// in [pair][dim] layout + 16 b64 reads + 30 adds) instead of R4's 112
// dependent DPP butterflies that blew up VALU (69% busy, 65us). Theory: R0's
// 49us was the per-CU LDS pipe at ~71% busy (~437 cy/node); this structure
// is ~220 cy/node LDS with VALU only +~75/node.
__launch_bounds__(64 * NPB, 8)
__global__ void gat_agg_kernel(const float* __restrict__ hidden,
                               const float* __restrict__ W,
                               const int* __restrict__ nbr,
                               const int* __restrict__ row_ptr,
                               const unsigned int* __restrict__ hb,
                               float* __restrict__ out,
                               int n, int P)
{
    __shared__ __align__(16) unsigned int s_hwp[NPB][ROWU];       // 0.42 KB
    __shared__ __align__(16) float        s_tr[NPB][CHUNK][TRW];  // 13.5 KB

    const int lane = threadIdx.x & 63;
    const int wid  = threadIdx.x >> 6;
    const int v    = blockIdx.x * NPB + wid;
    if (v >= n) return;          // wave-uniform exit; no block barriers used

    // hw[d] = hidden[v][d] * W[d] (fp32 product, f16-packed into LDS)
    if (lane < 50) {
        float2 h2 = ((const float2*)(hidden + (long)v * D))[lane];
        float2 w2 = ((const float2*)W)[lane];
        s_hwp[wid][lane] = pkh2(h2.x * w2.x, h2.y * w2.y);
    }
    COMPILER_FENCE();

    const int start = row_ptr[v];
    const int end   = row_ptr[v + 1];

    if (end <= start) {          // empty segment: zeros (matches reference)
        if (lane < D / 2)
            ((float2*)(out + (long)v * D))[lane] = make_float2(0.f, 0.f);
        return;
    }

    const int q  = lane >> 4;    // quarter 0..3: uint4s q*3..q*3+2 (+tail on q0)
    const int jl = lane & 15;    // pair slot within the 16-chunk
    const int t0 = q * 3;

    // hoist hw fragment into registers (loop-invariant; 14 regs)
    const uint4* hwq = ((const uint4*)&s_hwp[wid][0]) + t0;
    const uint4 a0 = hwq[0], a1 = hwq[1], a2 = hwq[2];
    uint2 at = make_uint2(0u, 0u);
    if (q == 0) at = *(const uint2*)&s_hwp[wid][48];

    // register accumulators: quarter dims 24q..24q+23, plus tail 96..99 on q0
    float accA[24];
    float accT[4];
    #pragma unroll
    for (int i = 0; i < 24; ++i) accA[i] = 0.f;
    #pragma unroll
    for (int i = 0; i < 4; ++i) accT[i] = 0.f;

    float m = -INFINITY, z = 0.f;

    for (int c = start; c < end; c += CHUNK) {
        const int  cnt = min(CHUNK, end - c);
        const bool pv  = jl < cnt;

        // neighbor index: coalesced masked load. invalid lanes use row 0
        // (finite, in-bounds, L1-hot); e=0 masks them later.
        const int nbv = pv ? nbr[c + jl] : 0;
        const uint4* row16 = ((const uint4*)hb) + nbv * (ROWU / 4) + t0;

        // ---- f16 quarter-row gather (3x16B + 8B tail on q0), fdot2 ----
        uint4 x0 = row16[0], x1 = row16[1], x2 = row16[2];
        uint2 xt = make_uint2(0u, 0u);
        if (q == 0) xt = *(const uint2*)&hb[nbv * ROWU + 48];   // dims 96..99

        float p0 = 0.f, p1 = 0.f, p2 = 0.f, p3 = 0.f;
        p0 = dot2u(a0.x, x0.x, p0);  p1 = dot2u(a0.y, x0.y, p1);
        p2 = dot2u(a0.z, x0.z, p2);  p3 = dot2u(a0.w, x0.w, p3);
        p0 = dot2u(a1.x, x1.x, p0);  p1 = dot2u(a1.y, x1.y, p1);
        p2 = dot2u(a1.z, x1.z, p2);  p3 = dot2u(a1.w, x1.w, p3);
        p0 = dot2u(a2.x, x2.x, p0);  p1 = dot2u(a2.y, x2.y, p1);
        p2 = dot2u(a2.z, x2.z, p2);  p3 = dot2u(a2.w, x2.w, p3);
        if (q == 0) {
            p0 = dot2u(at.x, xt.x, p0);
            p1 = dot2u(at.y, xt.y, p1);
        }

        float part = (p0 + p1) + (p2 + p3);
        part += __shfl_xor(part, 16, 64);    // combine quarters; after these
        part += __shfl_xor(part, 32, 64);    // ALL 4 lanes hold the pair score
        const float s = pv ? (part >= 0.f ? part : NEG_SLOPE * part)
                           : -INFINITY;

        // ---- online softmax over the 16 pairs (DPP trees, wave-uniform m) --
        const float m_new = fmaxf(m, red16_max(s));
        const float e     = pv ? __expf(s - m_new) : 0.f;
        const float gsum  = red16_sum(e);

        if (m_new != m) {                    // wave-uniform; scale==1 if equal
            const float scale = __expf(m - m_new);   // first chunk: 0
            z *= scale;
            #pragma unroll
            for (int i = 0; i < 24; ++i) accA[i] *= scale;
            #pragma unroll
            for (int i = 0; i < 4; ++i) accT[i] *= scale;
            m = m_new;
        }
        z += gsum;

        // ---- accumulate e * row into register accumulators (v_fma_mix) ----
        ACCU4(0,  x0);
        ACCU4(8,  x1);
        ACCU4(16, x2);
        if (q == 0) {
            U32H2 t_;
            t_.u = xt.x; accT[0] = fmaf((float)t_.h.x, e, accT[0]);
                         accT[1] = fmaf((float)t_.h.y, e, accT[1]);
            t_.u = xt.y; accT[2] = fmaf((float)t_.h.x, e, accT[2]);
                         accT[3] = fmaf((float)t_.h.y, e, accT[3]);
        }
    }

    // ---- epilogue: cross-pair reduction via ONE LDS transpose per node ----
    // write [pair jl][dim] rows: 6 b128 (quarter dims) + 1 b128 (tail, q0)
    float* trow = &s_tr[wid][jl][24 * q];
    *(float4*)&trow[0]  = make_float4(accA[0],  accA[1],  accA[2],  accA[3]);
    *(float4*)&trow[4]  = make_float4(accA[4],  accA[5],  accA[6],  accA[7]);
    *(float4*)&trow[8]  = make_float4(accA[8],  accA[9],  accA[10], accA[11]);
    *(float4*)&trow[12] = make_float4(accA[12], accA[13], accA[14], accA[15]);
    *(float4*)&trow[16] = make_float4(accA[16], accA[17], accA[18], accA[19]);
    *(float4*)&trow[20] = make_float4(accA[20], accA[21], accA[22], accA[23]);
    if (q == 0)
        *(float4*)&s_tr[wid][jl][96] =
            make_float4(accT[0], accT[1], accT[2], accT[3]);
    COMPILER_FENCE();            // same-wave LDS: pipe-ordered, fence compiler

    // lane d (0..49) sums dims (2d,2d+1) across the 16 pair rows, then stores
    if (lane < D / 2) {
        float sx = 0.f, sy = 0.f;
        #pragma unroll
        for (int p = 0; p < 16; ++p) {
            const float2 t = *(const float2*)&s_tr[wid][p][2 * lane];
            sx += t.x; sy += t.y;
        }
        const float inv = 1.f / z;           // z wave-uniform
        ((float2*)(out + (long)v * D))[lane] = make_float2(sx * inv, sy * inv);
    }
}

extern "C" void kernel_launch(void* const* d_in, const int* in_sizes, int n_in,
                              void* d_out, int out_size, void* d_ws, size_t ws_size,
                              hipStream_t stream) {
    const float* hidden = (const float*)d_in[0];
    const float* W      = (const float*)d_in[1];
    const int*   seg    = (const int*)d_in[2];
    const int*   nbr    = (const int*)d_in[3];
    float*       out    = (float*)d_out;

    const int Ddim = in_sizes[1];           // 100
    const int n    = in_sizes[0] / Ddim;    // 50000
    const int P    = in_sizes[2];           // ~1.3M pairs

    // ws layout: row_ptr (n+1 ints) | hb (n*ROWU uints, 256B-aligned)
    int* row_ptr = (int*)d_ws;
    size_t hb_off = (((size_t)(n + 1) * 4) + 255) & ~(size_t)255;
    unsigned int* hb = (unsigned int*)((char*)d_ws + hb_off);

    const int total25 = n * 25;             // float4-groups in hidden
    const int tmax    = (P > total25) ? P : total25;
    hipLaunchKernelGGL(prep_kernel, dim3((tmax + 255) / 256), dim3(256), 0, stream,
                       seg, row_ptr, hidden, hb, n, P, total25);
    hipLaunchKernelGGL(gat_agg_kernel, dim3((n + NPB - 1) / NPB), dim3(64 * NPB),
                       0, stream, hidden, W, nbr, row_ptr, hb, out, n, P);
}